// Round 16
// baseline (688.329 us; speedup 1.0000x reference)
//
#include <hip/hip_runtime.h>
#include <hip/hip_bf16.h>
#include <cstdint>
#include <cstddef>

// B=4, S=2048, D=1024, H=16, DH=64, M = B*S = 8192
#define S_ 2048
#define D_ 1024
#define H_ 16
#define DH_ 64
#define M_ 8192

using bf16 = __bf16;
using bf16x4 = __attribute__((ext_vector_type(4))) __bf16;
using bf16x8 = __attribute__((ext_vector_type(8))) __bf16;
using f32x4 = __attribute__((ext_vector_type(4))) float;
using s16x4 = __attribute__((ext_vector_type(4))) short;

__device__ __forceinline__ void g2lds16(const bf16* g, bf16* l) {
  __builtin_amdgcn_global_load_lds(
      (const __attribute__((address_space(1))) void*)g,
      (__attribute__((address_space(3))) void*)l, 16, 0, 0);
}

// 16x16x16 bf16 MFMA (used by attn PV)
__device__ __forceinline__ f32x4 mfma16(bf16x4 a, bf16x4 b, f32x4 c) {
#if __has_builtin(__builtin_amdgcn_mfma_f32_16x16x16_bf16)
  return __builtin_amdgcn_mfma_f32_16x16x16_bf16(a, b, c, 0, 0, 0);
#elif __has_builtin(__builtin_amdgcn_mfma_f32_16x16x16bf16_1k)
  return __builtin_amdgcn_mfma_f32_16x16x16bf16_1k(
      __builtin_bit_cast(s16x4, a), __builtin_bit_cast(s16x4, b), c, 0, 0, 0);
#else
  f32x4 d;
  asm("v_mfma_f32_16x16x16_bf16 %0, %1, %2, %3"
      : "=v"(d)
      : "v"(a), "v"(b), "v"(c));
  return d;
#endif
}

// ------- fused fp32->bf16 converts: x (blocks 0..4095) + 4 weights^T -------
__global__ __launch_bounds__(256) void cvt_all_kernel(
    const float* __restrict__ x, const float* __restrict__ w0,
    const float* __restrict__ w1, const float* __restrict__ w2,
    const float* __restrict__ w3, bf16* __restrict__ xb,
    bf16* __restrict__ o0, bf16* __restrict__ o1, bf16* __restrict__ o2,
    bf16* __restrict__ o3) {
  __shared__ float tile[32][33];
  int bx = blockIdx.x;
  int tid = threadIdx.x;
  if (bx < 4096) {
    size_t i = ((size_t)bx * 256 + tid) * 8;
    float4 a = *(const float4*)(x + i);
    float4 b = *(const float4*)(x + i + 4);
    bf16x8 o;
    o[0] = (bf16)a.x; o[1] = (bf16)a.y; o[2] = (bf16)a.z; o[3] = (bf16)a.w;
    o[4] = (bf16)b.x; o[5] = (bf16)b.y; o[6] = (bf16)b.z; o[7] = (bf16)b.w;
    *(bf16x8*)(xb + i) = o;
    return;
  }
  int wb = bx - 4096;
  int wsel = wb >> 10; wb &= 1023;
  const float* W; bf16* O;
  switch (wsel) {
    case 0: W = w0; O = o0; break;
    case 1: W = w1; O = o1; break;
    case 2: W = w2; O = o2; break;
    default: W = w3; O = o3; break;
  }
  int n0 = (wb & 31) * 32;
  int k0 = (wb >> 5) * 32;
#pragma unroll
  for (int i = 0; i < 4; ++i) {
    int e = tid + i * 256; int rr = e >> 5, cc = e & 31;
    tile[rr][cc] = W[(size_t)(k0 + rr) * 1024 + n0 + cc];
  }
  __syncthreads();
#pragma unroll
  for (int i = 0; i < 4; ++i) {
    int e = tid + i * 256; int rr = e >> 5, cc = e & 31;
    O[(size_t)(n0 + rr) * 1024 + k0 + cc] = (bf16)tile[cc][rr];
  }
}

// ======= GEMM-A v9 (QKV): 128x256, BK=32, 8 waves, DOUBLE-buffered =======
// Round-16: occupancy-round fix. 3x24KB (72KB) allowed only 2 blocks/CU,
// so grid 768 ran as 512 co-resident + a 256-block tail at 1 block/CU
// (the slow single-block regime). 2x24KB (48KB) -> 3 blocks/CU = exactly
// ONE residency round (768 = 3x256) and 6 waves/SIMD (was 4) for this
// stall-bound kernel. Sync = the race-hardened attn-v9 template (verified
// 8 rounds): per tile {vmcnt(0) lgkmcnt(0); barrier; stage(other);
// compute(cur)} -- stage target's readers all retired before the barrier;
// the landing is drained by the NEXT iteration's wait, one full
// compute-phase (~600cy >= L2 latency) after issue. Row-pair XOR swizzle
// unchanged (0 conflicts, round-13).
__global__ __launch_bounds__(512, 6) void gemmA_kernel(
    const bf16* __restrict__ A, const bf16* __restrict__ Bt0,
    const bf16* __restrict__ Bt1, const bf16* __restrict__ Bt2,
    bf16* __restrict__ Qo, bf16* __restrict__ Ko, bf16* __restrict__ Vto) {
  extern __shared__ float4 smem4[];
  bf16* smem = (bf16*)smem4;  // 2 buffers x 12288 elems (A 4096 + B 8192)

  const int wg = ((int)blockIdx.x & 7) * 96 + ((int)blockIdx.x >> 3);
  const int bn = wg % 12, bm = wg / 12;
  const int wsel = bn >> 2;
  const bf16* Bt = (wsel == 0) ? Bt0 : (wsel == 1 ? Bt1 : Bt2);
  const int n0full = (bn & 3) * 256;

  const int tid = threadIdx.x;
  const int wave = tid >> 6, lane = tid & 63;
  const int quad = lane >> 4, r = lane & 15;
  const int wm = (wave >> 2) * 64, wn = (wave & 3) * 64;

  const int lrow = lane >> 2;                             // 0..15
  const int lcol = ((lane & 3) ^ ((lrow >> 1) & 3)) * 8;  // row-pair swizzle
  const int am = bm * 128 + wave * 16 + lrow;
  const bf16* pA = A + (size_t)am * 1024 + lcol;
  const int bnr = n0full + wave * 16 + lrow;
  const bf16* pB1 = Bt + (size_t)bnr * 1024 + lcol;
  const bf16* pB2 = Bt + (size_t)(bnr + 128) * 1024 + lcol;

  const int oA = wave * 512;
  const int oB1 = 4096 + wave * 512;
  const int oB2 = 8192 + wave * 512;

  auto stage = [&](bf16* base) {
    g2lds16(pA, base + oA); pA += 32;
    g2lds16(pB1, base + oB1); pB1 += 32;
    g2lds16(pB2, base + oB2); pB2 += 32;
  };

  f32x4 acc[4][4];
  const f32x4 zero = {0.f, 0.f, 0.f, 0.f};
#pragma unroll
  for (int i = 0; i < 4; ++i)
#pragma unroll
    for (int j = 0; j < 4; ++j) acc[i][j] = zero;

  // reader: (row>>1)&3 == (r>>1)&3 for all frag rows (offsets mult of 16)
  const int x0 = (quad ^ ((r >> 1) & 3)) * 8;
  const int raB = (wm + r) * 32;
  const int rbB = (wn + r) * 32;

  auto phase = [&](const bf16* buf) {
    const bf16* bA = buf;
    const bf16* bB = buf + 4096;
    bf16x8 af[4], bg[4];
#pragma unroll
    for (int i = 0; i < 4; ++i)
      af[i] = *(const bf16x8*)(bA + raB + i * 512 + x0);
#pragma unroll
    for (int j = 0; j < 4; ++j)
      bg[j] = *(const bf16x8*)(bB + rbB + j * 512 + x0);
    __builtin_amdgcn_s_setprio(1);
#pragma unroll
    for (int i = 0; i < 4; ++i)
#pragma unroll
      for (int j = 0; j < 4; ++j)
        acc[i][j] = __builtin_amdgcn_mfma_f32_16x16x32_bf16(af[i], bg[j],
                                                            acc[i][j], 0, 0, 0);
    __builtin_amdgcn_s_setprio(0);
  };

  bf16* bufs[2] = {smem, smem + 12288};

  stage(bufs[0]);  // tile 0

#pragma unroll 1
  for (int kt = 0; kt < 32; ++kt) {
    // drain: tile kt's loads landed; all waves' reads of buf[kt&1^1]
    // (tile kt-1) retired before this barrier -> safe to restage it.
    asm volatile("s_waitcnt vmcnt(0) lgkmcnt(0)\n\ts_barrier" ::: "memory");
    if (kt + 1 < 32) stage(bufs[(kt + 1) & 1]);
    phase(bufs[kt & 1]);
  }

  // ---- epilogue ----
  const int mB = bm * 128 + wm + quad * 4;
  if (wsel < 2) {
    bf16* dst = (wsel == 0) ? Qo : Ko;
#pragma unroll
    for (int i = 0; i < 4; ++i) {
#pragma unroll
      for (int j = 0; j < 4; ++j) {
        int n = n0full + wn + j * 16 + r;
        int h = n >> 6, dh = n & 63;
#pragma unroll
        for (int g = 0; g < 4; ++g) {
          int m = mB + i * 16 + g;
          int b = m >> 11, s = m & 2047;
          dst[((size_t)(b * H_ + h) * S_ + s) * DH_ + dh] = (bf16)acc[i][j][g];
        }
      }
    }
  } else {  // V: store transposed [B,H,DH,S]
#pragma unroll
    for (int i = 0; i < 4; ++i) {
      int m = mB + i * 16;
      int b = m >> 11, s = m & 2047;
#pragma unroll
      for (int j = 0; j < 4; ++j) {
        int n = n0full + wn + j * 16 + r;
        int h = n >> 6, dh = n & 63;
        bf16x4 pk;
#pragma unroll
        for (int g = 0; g < 4; ++g) pk[g] = (bf16)acc[i][j][g];
        *(bf16x4*)(Vto + ((size_t)(b * H_ + h) * DH_ + dh) * S_ + s) = pk;
      }
    }
  }
}

// ======= GEMM-B (output proj): round-13 verified, unchanged =======
// (grid 256 is CU-limited, so the occupancy-round fix doesn't apply here;
// keep the proven 3-buffer vmcnt(3) form.)
__global__ __launch_bounds__(512, 4) void gemmB_kernel(
    const bf16* __restrict__ A, const bf16* __restrict__ Bt0,
    bf16* __restrict__ Qo) {
  extern __shared__ float4 smem4[];
  bf16* smem = (bf16*)smem4;  // 3 buffers x 12288 elems

  const int wg = ((int)blockIdx.x & 7) * 32 + ((int)blockIdx.x >> 3);
  const int bn = wg % 4, bm = wg / 4;
  const bf16* Bt = Bt0;
  const int n0full = bn * 256;

  const int tid = threadIdx.x;
  const int wave = tid >> 6, lane = tid & 63;
  const int quad = lane >> 4, r = lane & 15;
  const int wm = (wave >> 2) * 64, wn = (wave & 3) * 64;

  const int lrow = lane >> 2;
  const int lcol = ((lane & 3) ^ ((lrow >> 1) & 3)) * 8;
  const int am = bm * 128 + wave * 16 + lrow;
  const bf16* pA = A + (size_t)(am >> 11) * (16 * (size_t)S_ * DH_) +
                   (size_t)(am & 2047) * 64 + lcol;
  const int bnr = n0full + wave * 16 + lrow;
  const bf16* pB1 = Bt + (size_t)bnr * 1024 + lcol;
  const bf16* pB2 = Bt + (size_t)(bnr + 128) * 1024 + lcol;
  constexpr ptrdiff_t dSum = (ptrdiff_t)S_ * DH_;
  ptrdiff_t dTog = 32;

  const int oA = wave * 512;
  const int oB1 = 4096 + wave * 512;
  const int oB2 = 8192 + wave * 512;

  auto stage = [&](bf16* base) {
    g2lds16(pA, base + oA);
    g2lds16(pB1, base + oB1);
    g2lds16(pB2, base + oB2);
    pA += dTog; dTog = dSum - dTog;
    pB1 += 32; pB2 += 32;
  };

  f32x4 acc[4][4];
  const f32x4 zero = {0.f, 0.f, 0.f, 0.f};
#pragma unroll
  for (int i = 0; i < 4; ++i)
#pragma unroll
    for (int j = 0; j < 4; ++j) acc[i][j] = zero;

  const int x0 = (quad ^ ((r >> 1) & 3)) * 8;
  const int raB = (wm + r) * 32;
  const int rbB = (wn + r) * 32;

  auto phase = [&](const bf16* buf) {
    const bf16* bA = buf;
    const bf16* bB = buf + 4096;
    bf16x8 af[4], bg[4];
#pragma unroll
    for (int i = 0; i < 4; ++i)
      af[i] = *(const bf16x8*)(bA + raB + i * 512 + x0);
#pragma unroll
    for (int j = 0; j < 4; ++j)
      bg[j] = *(const bf16x8*)(bB + rbB + j * 512 + x0);
    __builtin_amdgcn_s_setprio(1);
#pragma unroll
    for (int i = 0; i < 4; ++i)
#pragma unroll
      for (int j = 0; j < 4; ++j)
        acc[i][j] = __builtin_amdgcn_mfma_f32_16x16x32_bf16(af[i], bg[j],
                                                            acc[i][j], 0, 0, 0);
    __builtin_amdgcn_s_setprio(0);
  };

  bf16* b0 = smem;
  bf16* b1 = smem + 12288;
  bf16* b2 = smem + 24576;

  stage(b0);
  stage(b1);

#pragma unroll 1
  for (int kt = 0; kt < 30; kt += 3) {
    asm volatile("s_waitcnt vmcnt(3)\n\ts_barrier" ::: "memory");
    stage(b2);
    phase(b0);
    asm volatile("s_waitcnt vmcnt(3)\n\ts_barrier" ::: "memory");
    stage(b0);
    phase(b1);
    asm volatile("s_waitcnt vmcnt(3)\n\ts_barrier" ::: "memory");
    stage(b1);
    phase(b2);
  }
  asm volatile("s_waitcnt vmcnt(3)\n\ts_barrier" ::: "memory");
  phase(b0);
  asm volatile("s_waitcnt vmcnt(0)\n\ts_barrier" ::: "memory");
  phase(b1);

  const int mB = bm * 128 + wm + quad * 4;
#pragma unroll
  for (int i = 0; i < 4; ++i) {
#pragma unroll
    for (int j = 0; j < 4; ++j) {
      int n = n0full + wn + j * 16 + r;
#pragma unroll
      for (int g = 0; g < 4; ++g) {
        int m = mB + i * 16 + g;
        Qo[(size_t)m * 1024 + n] = (bf16)acc[i][j][g];
      }
    }
  }
}

// ------ flash attention v12: v9 structure with 128-kv SYNC UNITS ------
// (unchanged; round-8..15 verified)
__global__ __launch_bounds__(512, 4) void attn_kernel(const bf16* __restrict__ Qb,
                                                      const bf16* __restrict__ Kb,
                                                      const bf16* __restrict__ Vtb,
                                                      bf16* __restrict__ ctx) {
  __shared__ __align__(16) bf16 smK[2][2][64 * 64];
  __shared__ __align__(16) bf16 smV[2][2][64 * 64];
  const int bx = blockIdx.x;
  const int bh = bx & 63;
  const int i256 = (bx < 256) ? (7 - (bx >> 6)) : ((bx - 256) >> 6);
  const bf16* Qh = Qb + (size_t)bh * S_ * DH_;
  const bf16* Kh = Kb + (size_t)bh * S_ * DH_;
  const bf16* Vh = Vtb + (size_t)bh * DH_ * S_;
  bf16* Ch = ctx + (size_t)bh * S_ * DH_;
  const int tid = threadIdx.x, wave = tid >> 6, lane = tid & 63;
  const int quad = lane >> 4, r = lane & 15;
  const int r7 = r & 7;
  const int wrow = wave * 8 + (lane >> 3);
  const int gcol = ((lane & 7) ^ (lane >> 3)) * 8;
  const f32x4 zero = {0.f, 0.f, 0.f, 0.f};
  const int xk0 = (quad ^ r7) * 8, xk1 = ((quad + 4) ^ r7) * 8;

  const int q0w = i256 * 256 + wave * 32;
  const int numkt = 4 * i256 + 4;
  const int NU = numkt >> 1;
  const int lastkt = q0w >> 6;

  bf16x8 qf[2][2];
  const float qsc = 0.125f * 1.44269504f;
#pragma unroll
  for (int qg = 0; qg < 2; ++qg)
#pragma unroll
    for (int hh = 0; hh < 2; ++hh) {
      bf16x8 q = *(const bf16x8*)(Qh + (size_t)(q0w + qg * 16 + r) * DH_ +
                                  hh * 32 + quad * 8);
#pragma unroll
      for (int i = 0; i < 8; ++i) q[i] = (bf16)((float)q[i] * qsc);
      qf[qg][hh] = q;
    }

  f32x4 lacc[2] = {zero, zero};
  f32x4 oacc[2][4];
#pragma unroll
  for (int qg = 0; qg < 2; ++qg)
#pragma unroll
    for (int tn = 0; tn < 4; ++tn) oacc[qg][tn] = zero;

  auto STAGE = [&](int u, int b) {
#pragma unroll
    for (int sub = 0; sub < 2; ++sub) {
      const int kt = 2 * u + sub;
      g2lds16(Kh + (size_t)(kt * 64 + wrow) * DH_ + gcol,
              &smK[b][sub][wave * 512]);
      g2lds16(Vh + (size_t)wrow * S_ + kt * 64 + gcol,
              &smV[b][sub][wave * 512]);
    }
  };

  STAGE(0, 0);
  asm volatile("s_waitcnt vmcnt(0)\n\ts_barrier" ::: "memory");

#pragma unroll 1
  for (int u = 0; u < NU; ++u) {
    const int b = u & 1;
    if (u + 1 < NU) STAGE(u + 1, b ^ 1);
#pragma unroll
    for (int sub = 0; sub < 2; ++sub) {
      const int kt = 2 * u + sub;
      if (kt <= lastkt) {
        const int kv0 = kt * 64;
        const bf16* kb = &smK[b][sub][0];
        const bf16* vb = &smV[b][sub][0];

        f32x4 s[2][4];
#pragma unroll
        for (int t = 0; t < 4; ++t) {
          bf16x8 kf0 = *(const bf16x8*)(kb + (t * 16 + r) * 64 + xk0);
          bf16x8 kf1 = *(const bf16x8*)(kb + (t * 16 + r) * 64 + xk1);
#pragma unroll
          for (int qg = 0; qg < 2; ++qg) {
            f32x4 z = __builtin_amdgcn_mfma_f32_16x16x32_bf16(kf0, qf[qg][0],
                                                              zero, 0, 0, 0);
            s[qg][t] = __builtin_amdgcn_mfma_f32_16x16x32_bf16(kf1, qf[qg][1],
                                                               z, 0, 0, 0);
          }
        }
        if (kt == lastkt) {
#pragma unroll
          for (int qg = 0; qg < 2; ++qg) {
            const int q = q0w + qg * 16 + r;
#pragma unroll
            for (int t = 0; t < 4; ++t) {
              const int kv = kv0 + t * 16 + quad * 4;
#pragma unroll
              for (int g = 0; g < 4; ++g)
                if (kv + g > q) s[qg][t][g] = -1e30f;
            }
          }
        }
#pragma unroll
        for (int t = 0; t < 4; ++t) {
          bf16x4 pa[2];
#pragma unroll
          for (int qg = 0; qg < 2; ++qg) {
#pragma unroll
            for (int g = 0; g < 4; ++g)
              s[qg][t][g] = __builtin_amdgcn_exp2f(s[qg][t][g]);
            lacc[qg] += s[qg][t];
            bf16x4 pk;
#pragma unroll
            for (int g = 0; g < 4; ++g) pk[g] = (bf16)s[qg][t][g];
            pa[qg] = pk;
          }
#pragma unroll
          for (int tn = 0; tn < 4; ++tn) {
            bf16x4 vf = *(const bf16x4*)(
                vb + (tn * 16 + r) * 64 +
                ((2 * t + (quad >> 1)) ^ r7) * 8 + (quad & 1) * 4);
            oacc[0][tn] = mfma16(pa[0], vf, oacc[0][tn]);
            oacc[1][tn] = mfma16(pa[1], vf, oacc[1][tn]);
          }
        }
      }
    }
    asm volatile("s_waitcnt vmcnt(0) lgkmcnt(0)\n\ts_barrier" ::: "memory");
  }

#pragma unroll
  for (int qg = 0; qg < 2; ++qg) {
    float rs = (lacc[qg][0] + lacc[qg][1]) + (lacc[qg][2] + lacc[qg][3]);
    rs += __shfl_xor(rs, 16, 64);
    rs += __shfl_xor(rs, 32, 64);
    const float inv = 1.f / rs;
    f32x4 ib;
#pragma unroll
    for (int g = 0; g < 4; ++g) ib[g] = __shfl(inv, quad * 4 + g, 64);
#pragma unroll
    for (int tn = 0; tn < 4; ++tn) {
      f32x4 ov = oacc[qg][tn] * ib;
#pragma unroll
      for (int g = 0; g < 4; ++g)
        Ch[(size_t)(q0w + qg * 16 + quad * 4 + g) * DH_ + tn * 16 + r] =
            (bf16)ov[g];
    }
  }
}

// ------- LayerNorm v3: out = LN(xb_bf16 + proj_bf16) * gamma + beta -------
__global__ __launch_bounds__(256) void ln_kernel(float* __restrict__ out,
                                                 const bf16* __restrict__ pb,
                                                 const bf16* __restrict__ xb,
                                                 const float* __restrict__ gamma,
                                                 const float* __restrict__ beta) {
  __shared__ float red[8];
  size_t row = blockIdx.x;
  int tid = threadIdx.x;
  bf16x4 xv = *(const bf16x4*)(xb + row * 1024 + tid * 4);
  bf16x4 pv = *(const bf16x4*)(pb + row * 1024 + tid * 4);
  float v0 = (float)xv[0] + (float)pv[0];
  float v1 = (float)xv[1] + (float)pv[1];
  float v2 = (float)xv[2] + (float)pv[2];
  float v3 = (float)xv[3] + (float)pv[3];
  float s1 = v0 + v1 + v2 + v3;
  float s2 = v0 * v0 + v1 * v1 + v2 * v2 + v3 * v3;
#pragma unroll
  for (int o = 1; o < 64; o <<= 1) {
    s1 += __shfl_xor(s1, o, 64);
    s2 += __shfl_xor(s2, o, 64);
  }
  int wave = tid >> 6, lane = tid & 63;
  if (lane == 0) { red[wave] = s1; red[4 + wave] = s2; }
  __syncthreads();
  s1 = red[0] + red[1] + red[2] + red[3];
  s2 = red[4] + red[5] + red[6] + red[7];
  float mean = s1 * (1.f / 1024.f);
  float var = s2 * (1.f / 1024.f) - mean * mean;
  float rstd = rsqrtf(var + 1e-5f);
  float4 g = ((const float4*)gamma)[tid];
  float4 b = ((const float4*)beta)[tid];
  float4 o;
  o.x = (v0 - mean) * rstd * g.x + b.x;
  o.y = (v1 - mean) * rstd * g.y + b.y;
  o.z = (v2 - mean) * rstd * g.z + b.z;
  o.w = (v3 - mean) * rstd * g.w + b.w;
  ((float4*)(out + row * 1024))[tid] = o;
}

extern "C" void kernel_launch(void* const* d_in, const int* in_sizes, int n_in,
                              void* d_out, int out_size, void* d_ws,
                              size_t ws_size, hipStream_t stream) {
  (void)in_sizes; (void)n_in; (void)out_size; (void)ws_size;
  const float* x  = (const float*)d_in[0];
  const float* WQ = (const float*)d_in[1];
  const float* WK = (const float*)d_in[2];
  const float* WV = (const float*)d_in[3];
  const float* WO = (const float*)d_in[4];
  const float* gamma = (const float*)d_in[5];
  const float* beta  = (const float*)d_in[6];
  float* out = (float*)d_out;

  bf16* ws = (bf16*)d_ws;
  const size_t MD = (size_t)M_ * D_;
  const size_t WW = (size_t)D_ * D_;
  bf16* xb   = ws;
  bf16* wqt  = xb + MD;
  bf16* wkt  = wqt + WW;
  bf16* wvt  = wkt + WW;
  bf16* wot  = wvt + WW;
  bf16* Qb   = wot + WW;
  bf16* Kb   = Qb + MD;
  bf16* Vtb  = Kb + MD;
  bf16* ctxb = Vtb + MD;
  // proj result (bf16) reuses Qb -- dead after attn_kernel.
  bf16* projb = Qb;

  constexpr int GEMMA_LDS = 2 * 24 * 1024;  // 49152 B -> 3 blocks/CU
  constexpr int GEMMB_LDS = 3 * 24 * 1024;  // 73728 B
  static bool s_attr = false;
  if (!s_attr) {
    s_attr = true;
    (void)hipFuncSetAttribute(reinterpret_cast<const void*>(gemmA_kernel),
                              hipFuncAttributeMaxDynamicSharedMemorySize,
                              GEMMA_LDS);
    (void)hipFuncSetAttribute(reinterpret_cast<const void*>(gemmB_kernel),
                              hipFuncAttributeMaxDynamicSharedMemorySize,
                              GEMMB_LDS);
  }

  cvt_all_kernel<<<dim3(8192), dim3(256), 0, stream>>>(
      x, WQ, WK, WV, WO, xb, wqt, wkt, wvt, wot);
  gemmA_kernel<<<dim3(768), dim3(512), GEMMA_LDS, stream>>>(
      xb, wqt, wkt, wvt, Qb, Kb, Vtb);
  attn_kernel<<<dim3(512), dim3(512), 0, stream>>>(Qb, Kb, Vtb, ctxb);
  gemmB_kernel<<<dim3(256), dim3(512), GEMMB_LDS, stream>>>(
      ctxb, wot, projb);
  ln_kernel<<<dim3(8192), dim3(256), 0, stream>>>(out, projb, xb, gamma, beta);
}

// Round 17
// 237.312 us; speedup vs baseline: 2.9005x; 2.9005x over previous
//
#include <hip/hip_runtime.h>
#include <hip/hip_bf16.h>
#include <cstdint>
#include <cstddef>

// B=4, S=2048, D=1024, H=16, DH=64, M = B*S = 8192
#define S_ 2048
#define D_ 1024
#define H_ 16
#define DH_ 64
#define M_ 8192

using bf16 = __bf16;
using bf16x4 = __attribute__((ext_vector_type(4))) __bf16;
using bf16x8 = __attribute__((ext_vector_type(8))) __bf16;
using f32x4 = __attribute__((ext_vector_type(4))) float;
using s16x4 = __attribute__((ext_vector_type(4))) short;

__device__ __forceinline__ void g2lds16(const bf16* g, bf16* l) {
  __builtin_amdgcn_global_load_lds(
      (const __attribute__((address_space(1))) void*)g,
      (__attribute__((address_space(3))) void*)l, 16, 0, 0);
}

// 16x16x16 bf16 MFMA (used by attn PV)
__device__ __forceinline__ f32x4 mfma16(bf16x4 a, bf16x4 b, f32x4 c) {
#if __has_builtin(__builtin_amdgcn_mfma_f32_16x16x16_bf16)
  return __builtin_amdgcn_mfma_f32_16x16x16_bf16(a, b, c, 0, 0, 0);
#elif __has_builtin(__builtin_amdgcn_mfma_f32_16x16x16bf16_1k)
  return __builtin_amdgcn_mfma_f32_16x16x16bf16_1k(
      __builtin_bit_cast(s16x4, a), __builtin_bit_cast(s16x4, b), c, 0, 0, 0);
#else
  f32x4 d;
  asm("v_mfma_f32_16x16x16_bf16 %0, %1, %2, %3"
      : "=v"(d)
      : "v"(a), "v"(b), "v"(c));
  return d;
#endif
}

// ------- fused fp32->bf16 converts: x (blocks 0..4095) + 4 weights^T -------
__global__ __launch_bounds__(256) void cvt_all_kernel(
    const float* __restrict__ x, const float* __restrict__ w0,
    const float* __restrict__ w1, const float* __restrict__ w2,
    const float* __restrict__ w3, bf16* __restrict__ xb,
    bf16* __restrict__ o0, bf16* __restrict__ o1, bf16* __restrict__ o2,
    bf16* __restrict__ o3) {
  __shared__ float tile[32][33];
  int bx = blockIdx.x;
  int tid = threadIdx.x;
  if (bx < 4096) {
    size_t i = ((size_t)bx * 256 + tid) * 8;
    float4 a = *(const float4*)(x + i);
    float4 b = *(const float4*)(x + i + 4);
    bf16x8 o;
    o[0] = (bf16)a.x; o[1] = (bf16)a.y; o[2] = (bf16)a.z; o[3] = (bf16)a.w;
    o[4] = (bf16)b.x; o[5] = (bf16)b.y; o[6] = (bf16)b.z; o[7] = (bf16)b.w;
    *(bf16x8*)(xb + i) = o;
    return;
  }
  int wb = bx - 4096;
  int wsel = wb >> 10; wb &= 1023;
  const float* W; bf16* O;
  switch (wsel) {
    case 0: W = w0; O = o0; break;
    case 1: W = w1; O = o1; break;
    case 2: W = w2; O = o2; break;
    default: W = w3; O = o3; break;
  }
  int n0 = (wb & 31) * 32;
  int k0 = (wb >> 5) * 32;
#pragma unroll
  for (int i = 0; i < 4; ++i) {
    int e = tid + i * 256; int rr = e >> 5, cc = e & 31;
    tile[rr][cc] = W[(size_t)(k0 + rr) * 1024 + n0 + cc];
  }
  __syncthreads();
#pragma unroll
  for (int i = 0; i < 4; ++i) {
    int e = tid + i * 256; int rr = e >> 5, cc = e & 31;
    O[(size_t)(n0 + rr) * 1024 + k0 + cc] = (bf16)tile[cc][rr];
  }
}

// ======= GEMM-A (QKV): round-13/15 verified geometry (final) =======
// 128x256 tile, BK=32, 8 waves (2M x 4N, 64x64 each), triple-buffered
// LDS 3 x 24KB -> 2 blocks/CU (4 waves/SIMD), vmcnt(3) counted waits,
// no mid-tile barrier, row-pair XOR swizzle (0 conflicts, 61.5us).
// Round-16's launch_bounds(512,6) 2-buffer variant spilled acc to
// scratch (VGPR cap 85 < 64 acc + operands): 514us, 2.45GB scratch
// traffic. 4 waves/SIMD is the register-feasible occupancy ceiling.
__global__ __launch_bounds__(512, 4) void gemmA_kernel(
    const bf16* __restrict__ A, const bf16* __restrict__ Bt0,
    const bf16* __restrict__ Bt1, const bf16* __restrict__ Bt2,
    bf16* __restrict__ Qo, bf16* __restrict__ Ko, bf16* __restrict__ Vto) {
  extern __shared__ float4 smem4[];
  bf16* smem = (bf16*)smem4;  // 3 buffers x 12288 elems (A 4096 + B 8192)

  const int wg = ((int)blockIdx.x & 7) * 96 + ((int)blockIdx.x >> 3);
  const int bn = wg % 12, bm = wg / 12;
  const int wsel = bn >> 2;
  const bf16* Bt = (wsel == 0) ? Bt0 : (wsel == 1 ? Bt1 : Bt2);
  const int n0full = (bn & 3) * 256;

  const int tid = threadIdx.x;
  const int wave = tid >> 6, lane = tid & 63;
  const int quad = lane >> 4, r = lane & 15;
  const int wm = (wave >> 2) * 64, wn = (wave & 3) * 64;

  const int lrow = lane >> 2;                             // 0..15
  const int lcol = ((lane & 3) ^ ((lrow >> 1) & 3)) * 8;  // row-pair swizzle
  const int am = bm * 128 + wave * 16 + lrow;
  const bf16* pA = A + (size_t)am * 1024 + lcol;
  const int bnr = n0full + wave * 16 + lrow;
  const bf16* pB1 = Bt + (size_t)bnr * 1024 + lcol;
  const bf16* pB2 = Bt + (size_t)(bnr + 128) * 1024 + lcol;

  const int oA = wave * 512;
  const int oB1 = 4096 + wave * 512;
  const int oB2 = 8192 + wave * 512;

  auto stage = [&](bf16* base) {
    g2lds16(pA, base + oA); pA += 32;
    g2lds16(pB1, base + oB1); pB1 += 32;
    g2lds16(pB2, base + oB2); pB2 += 32;
  };

  f32x4 acc[4][4];
  const f32x4 zero = {0.f, 0.f, 0.f, 0.f};
#pragma unroll
  for (int i = 0; i < 4; ++i)
#pragma unroll
    for (int j = 0; j < 4; ++j) acc[i][j] = zero;

  // reader: (row>>1)&3 == (r>>1)&3 for all frag rows (offsets mult of 16)
  const int x0 = (quad ^ ((r >> 1) & 3)) * 8;
  const int raB = (wm + r) * 32;
  const int rbB = (wn + r) * 32;

  auto phase = [&](const bf16* buf) {
    const bf16* bA = buf;
    const bf16* bB = buf + 4096;
    bf16x8 af[4], bg[4];
#pragma unroll
    for (int i = 0; i < 4; ++i)
      af[i] = *(const bf16x8*)(bA + raB + i * 512 + x0);
#pragma unroll
    for (int j = 0; j < 4; ++j)
      bg[j] = *(const bf16x8*)(bB + rbB + j * 512 + x0);
    __builtin_amdgcn_s_setprio(1);
#pragma unroll
    for (int i = 0; i < 4; ++i)
#pragma unroll
      for (int j = 0; j < 4; ++j)
        acc[i][j] = __builtin_amdgcn_mfma_f32_16x16x32_bf16(af[i], bg[j],
                                                            acc[i][j], 0, 0, 0);
    __builtin_amdgcn_s_setprio(0);
  };

  bf16* b0 = smem;
  bf16* b1 = smem + 12288;
  bf16* b2 = smem + 24576;

  stage(b0);  // tile 0
  stage(b1);  // tile 1

#pragma unroll 1
  for (int kt = 0; kt < 30; kt += 3) {
    asm volatile("s_waitcnt vmcnt(3)\n\ts_barrier" ::: "memory");
    stage(b2);
    phase(b0);
    asm volatile("s_waitcnt vmcnt(3)\n\ts_barrier" ::: "memory");
    stage(b0);
    phase(b1);
    asm volatile("s_waitcnt vmcnt(3)\n\ts_barrier" ::: "memory");
    stage(b1);
    phase(b2);
  }
  asm volatile("s_waitcnt vmcnt(3)\n\ts_barrier" ::: "memory");
  phase(b0);                      // tile 30
  asm volatile("s_waitcnt vmcnt(0)\n\ts_barrier" ::: "memory");
  phase(b1);                      // tile 31

  // ---- epilogue ----
  const int mB = bm * 128 + wm + quad * 4;
  if (wsel < 2) {
    bf16* dst = (wsel == 0) ? Qo : Ko;
#pragma unroll
    for (int i = 0; i < 4; ++i) {
#pragma unroll
      for (int j = 0; j < 4; ++j) {
        int n = n0full + wn + j * 16 + r;
        int h = n >> 6, dh = n & 63;
#pragma unroll
        for (int g = 0; g < 4; ++g) {
          int m = mB + i * 16 + g;
          int b = m >> 11, s = m & 2047;
          dst[((size_t)(b * H_ + h) * S_ + s) * DH_ + dh] = (bf16)acc[i][j][g];
        }
      }
    }
  } else {  // V: store transposed [B,H,DH,S]
#pragma unroll
    for (int i = 0; i < 4; ++i) {
      int m = mB + i * 16;
      int b = m >> 11, s = m & 2047;
#pragma unroll
      for (int j = 0; j < 4; ++j) {
        int n = n0full + wn + j * 16 + r;
        int h = n >> 6, dh = n & 63;
        bf16x4 pk;
#pragma unroll
        for (int g = 0; g < 4; ++g) pk[g] = (bf16)acc[i][j][g];
        *(bf16x4*)(Vto + ((size_t)(b * H_ + h) * DH_ + dh) * S_ + s) = pk;
      }
    }
  }
}

// ======= GEMM-B (output proj): round-13 verified, unchanged =======
// 128x256 tile, BK=32, 8 waves 64x64, 3x24KB, vmcnt(3), row-pair swizzle.
// Writes proj as bf16 (no residual) to Qo; ln adds the residual.
__global__ __launch_bounds__(512, 4) void gemmB_kernel(
    const bf16* __restrict__ A, const bf16* __restrict__ Bt0,
    bf16* __restrict__ Qo) {
  extern __shared__ float4 smem4[];
  bf16* smem = (bf16*)smem4;  // 3 buffers x 12288 elems

  const int wg = ((int)blockIdx.x & 7) * 32 + ((int)blockIdx.x >> 3);
  const int bn = wg % 4, bm = wg / 4;
  const bf16* Bt = Bt0;
  const int n0full = bn * 256;

  const int tid = threadIdx.x;
  const int wave = tid >> 6, lane = tid & 63;
  const int quad = lane >> 4, r = lane & 15;
  const int wm = (wave >> 2) * 64, wn = (wave & 3) * 64;

  const int lrow = lane >> 2;
  const int lcol = ((lane & 3) ^ ((lrow >> 1) & 3)) * 8;
  const int am = bm * 128 + wave * 16 + lrow;
  const bf16* pA = A + (size_t)(am >> 11) * (16 * (size_t)S_ * DH_) +
                   (size_t)(am & 2047) * 64 + lcol;
  const int bnr = n0full + wave * 16 + lrow;
  const bf16* pB1 = Bt + (size_t)bnr * 1024 + lcol;
  const bf16* pB2 = Bt + (size_t)(bnr + 128) * 1024 + lcol;
  constexpr ptrdiff_t dSum = (ptrdiff_t)S_ * DH_;
  ptrdiff_t dTog = 32;

  const int oA = wave * 512;
  const int oB1 = 4096 + wave * 512;
  const int oB2 = 8192 + wave * 512;

  auto stage = [&](bf16* base) {
    g2lds16(pA, base + oA);
    g2lds16(pB1, base + oB1);
    g2lds16(pB2, base + oB2);
    pA += dTog; dTog = dSum - dTog;
    pB1 += 32; pB2 += 32;
  };

  f32x4 acc[4][4];
  const f32x4 zero = {0.f, 0.f, 0.f, 0.f};
#pragma unroll
  for (int i = 0; i < 4; ++i)
#pragma unroll
    for (int j = 0; j < 4; ++j) acc[i][j] = zero;

  const int x0 = (quad ^ ((r >> 1) & 3)) * 8;
  const int raB = (wm + r) * 32;
  const int rbB = (wn + r) * 32;

  auto phase = [&](const bf16* buf) {
    const bf16* bA = buf;
    const bf16* bB = buf + 4096;
    bf16x8 af[4], bg[4];
#pragma unroll
    for (int i = 0; i < 4; ++i)
      af[i] = *(const bf16x8*)(bA + raB + i * 512 + x0);
#pragma unroll
    for (int j = 0; j < 4; ++j)
      bg[j] = *(const bf16x8*)(bB + rbB + j * 512 + x0);
    __builtin_amdgcn_s_setprio(1);
#pragma unroll
    for (int i = 0; i < 4; ++i)
#pragma unroll
      for (int j = 0; j < 4; ++j)
        acc[i][j] = __builtin_amdgcn_mfma_f32_16x16x32_bf16(af[i], bg[j],
                                                            acc[i][j], 0, 0, 0);
    __builtin_amdgcn_s_setprio(0);
  };

  bf16* b0 = smem;
  bf16* b1 = smem + 12288;
  bf16* b2 = smem + 24576;

  stage(b0);
  stage(b1);

#pragma unroll 1
  for (int kt = 0; kt < 30; kt += 3) {
    asm volatile("s_waitcnt vmcnt(3)\n\ts_barrier" ::: "memory");
    stage(b2);
    phase(b0);
    asm volatile("s_waitcnt vmcnt(3)\n\ts_barrier" ::: "memory");
    stage(b0);
    phase(b1);
    asm volatile("s_waitcnt vmcnt(3)\n\ts_barrier" ::: "memory");
    stage(b1);
    phase(b2);
  }
  asm volatile("s_waitcnt vmcnt(3)\n\ts_barrier" ::: "memory");
  phase(b0);
  asm volatile("s_waitcnt vmcnt(0)\n\ts_barrier" ::: "memory");
  phase(b1);

  const int mB = bm * 128 + wm + quad * 4;
#pragma unroll
  for (int i = 0; i < 4; ++i) {
#pragma unroll
    for (int j = 0; j < 4; ++j) {
      int n = n0full + wn + j * 16 + r;
#pragma unroll
      for (int g = 0; g < 4; ++g) {
        int m = mB + i * 16 + g;
        Qo[(size_t)m * 1024 + n] = (bf16)acc[i][j][g];
      }
    }
  }
}

// ------ flash attention v12: v9 structure with 128-kv SYNC UNITS ------
// (unchanged; round-8..15 verified)
__global__ __launch_bounds__(512, 4) void attn_kernel(const bf16* __restrict__ Qb,
                                                      const bf16* __restrict__ Kb,
                                                      const bf16* __restrict__ Vtb,
                                                      bf16* __restrict__ ctx) {
  __shared__ __align__(16) bf16 smK[2][2][64 * 64];
  __shared__ __align__(16) bf16 smV[2][2][64 * 64];
  const int bx = blockIdx.x;
  const int bh = bx & 63;
  const int i256 = (bx < 256) ? (7 - (bx >> 6)) : ((bx - 256) >> 6);
  const bf16* Qh = Qb + (size_t)bh * S_ * DH_;
  const bf16* Kh = Kb + (size_t)bh * S_ * DH_;
  const bf16* Vh = Vtb + (size_t)bh * DH_ * S_;
  bf16* Ch = ctx + (size_t)bh * S_ * DH_;
  const int tid = threadIdx.x, wave = tid >> 6, lane = tid & 63;
  const int quad = lane >> 4, r = lane & 15;
  const int r7 = r & 7;
  const int wrow = wave * 8 + (lane >> 3);
  const int gcol = ((lane & 7) ^ (lane >> 3)) * 8;
  const f32x4 zero = {0.f, 0.f, 0.f, 0.f};
  const int xk0 = (quad ^ r7) * 8, xk1 = ((quad + 4) ^ r7) * 8;

  const int q0w = i256 * 256 + wave * 32;
  const int numkt = 4 * i256 + 4;
  const int NU = numkt >> 1;
  const int lastkt = q0w >> 6;

  bf16x8 qf[2][2];
  const float qsc = 0.125f * 1.44269504f;
#pragma unroll
  for (int qg = 0; qg < 2; ++qg)
#pragma unroll
    for (int hh = 0; hh < 2; ++hh) {
      bf16x8 q = *(const bf16x8*)(Qh + (size_t)(q0w + qg * 16 + r) * DH_ +
                                  hh * 32 + quad * 8);
#pragma unroll
      for (int i = 0; i < 8; ++i) q[i] = (bf16)((float)q[i] * qsc);
      qf[qg][hh] = q;
    }

  f32x4 lacc[2] = {zero, zero};
  f32x4 oacc[2][4];
#pragma unroll
  for (int qg = 0; qg < 2; ++qg)
#pragma unroll
    for (int tn = 0; tn < 4; ++tn) oacc[qg][tn] = zero;

  auto STAGE = [&](int u, int b) {
#pragma unroll
    for (int sub = 0; sub < 2; ++sub) {
      const int kt = 2 * u + sub;
      g2lds16(Kh + (size_t)(kt * 64 + wrow) * DH_ + gcol,
              &smK[b][sub][wave * 512]);
      g2lds16(Vh + (size_t)wrow * S_ + kt * 64 + gcol,
              &smV[b][sub][wave * 512]);
    }
  };

  STAGE(0, 0);
  asm volatile("s_waitcnt vmcnt(0)\n\ts_barrier" ::: "memory");

#pragma unroll 1
  for (int u = 0; u < NU; ++u) {
    const int b = u & 1;
    if (u + 1 < NU) STAGE(u + 1, b ^ 1);
#pragma unroll
    for (int sub = 0; sub < 2; ++sub) {
      const int kt = 2 * u + sub;
      if (kt <= lastkt) {
        const int kv0 = kt * 64;
        const bf16* kb = &smK[b][sub][0];
        const bf16* vb = &smV[b][sub][0];

        f32x4 s[2][4];
#pragma unroll
        for (int t = 0; t < 4; ++t) {
          bf16x8 kf0 = *(const bf16x8*)(kb + (t * 16 + r) * 64 + xk0);
          bf16x8 kf1 = *(const bf16x8*)(kb + (t * 16 + r) * 64 + xk1);
#pragma unroll
          for (int qg = 0; qg < 2; ++qg) {
            f32x4 z = __builtin_amdgcn_mfma_f32_16x16x32_bf16(kf0, qf[qg][0],
                                                              zero, 0, 0, 0);
            s[qg][t] = __builtin_amdgcn_mfma_f32_16x16x32_bf16(kf1, qf[qg][1],
                                                               z, 0, 0, 0);
          }
        }
        if (kt == lastkt) {
#pragma unroll
          for (int qg = 0; qg < 2; ++qg) {
            const int q = q0w + qg * 16 + r;
#pragma unroll
            for (int t = 0; t < 4; ++t) {
              const int kv = kv0 + t * 16 + quad * 4;
#pragma unroll
              for (int g = 0; g < 4; ++g)
                if (kv + g > q) s[qg][t][g] = -1e30f;
            }
          }
        }
#pragma unroll
        for (int t = 0; t < 4; ++t) {
          bf16x4 pa[2];
#pragma unroll
          for (int qg = 0; qg < 2; ++qg) {
#pragma unroll
            for (int g = 0; g < 4; ++g)
              s[qg][t][g] = __builtin_amdgcn_exp2f(s[qg][t][g]);
            lacc[qg] += s[qg][t];
            bf16x4 pk;
#pragma unroll
            for (int g = 0; g < 4; ++g) pk[g] = (bf16)s[qg][t][g];
            pa[qg] = pk;
          }
#pragma unroll
          for (int tn = 0; tn < 4; ++tn) {
            bf16x4 vf = *(const bf16x4*)(
                vb + (tn * 16 + r) * 64 +
                ((2 * t + (quad >> 1)) ^ r7) * 8 + (quad & 1) * 4);
            oacc[0][tn] = mfma16(pa[0], vf, oacc[0][tn]);
            oacc[1][tn] = mfma16(pa[1], vf, oacc[1][tn]);
          }
        }
      }
    }
    asm volatile("s_waitcnt vmcnt(0) lgkmcnt(0)\n\ts_barrier" ::: "memory");
  }

#pragma unroll
  for (int qg = 0; qg < 2; ++qg) {
    float rs = (lacc[qg][0] + lacc[qg][1]) + (lacc[qg][2] + lacc[qg][3]);
    rs += __shfl_xor(rs, 16, 64);
    rs += __shfl_xor(rs, 32, 64);
    const float inv = 1.f / rs;
    f32x4 ib;
#pragma unroll
    for (int g = 0; g < 4; ++g) ib[g] = __shfl(inv, quad * 4 + g, 64);
#pragma unroll
    for (int tn = 0; tn < 4; ++tn) {
      f32x4 ov = oacc[qg][tn] * ib;
#pragma unroll
      for (int g = 0; g < 4; ++g)
        Ch[(size_t)(q0w + qg * 16 + quad * 4 + g) * DH_ + tn * 16 + r] =
            (bf16)ov[g];
    }
  }
}

// ------- LayerNorm v3: out = LN(xb_bf16 + proj_bf16) * gamma + beta -------
__global__ __launch_bounds__(256) void ln_kernel(float* __restrict__ out,
                                                 const bf16* __restrict__ pb,
                                                 const bf16* __restrict__ xb,
                                                 const float* __restrict__ gamma,
                                                 const float* __restrict__ beta) {
  __shared__ float red[8];
  size_t row = blockIdx.x;
  int tid = threadIdx.x;
  bf16x4 xv = *(const bf16x4*)(xb + row * 1024 + tid * 4);
  bf16x4 pv = *(const bf16x4*)(pb + row * 1024 + tid * 4);
  float v0 = (float)xv[0] + (float)pv[0];
  float v1 = (float)xv[1] + (float)pv[1];
  float v2 = (float)xv[2] + (float)pv[2];
  float v3 = (float)xv[3] + (float)pv[3];
  float s1 = v0 + v1 + v2 + v3;
  float s2 = v0 * v0 + v1 * v1 + v2 * v2 + v3 * v3;
#pragma unroll
  for (int o = 1; o < 64; o <<= 1) {
    s1 += __shfl_xor(s1, o, 64);
    s2 += __shfl_xor(s2, o, 64);
  }
  int wave = tid >> 6, lane = tid & 63;
  if (lane == 0) { red[wave] = s1; red[4 + wave] = s2; }
  __syncthreads();
  s1 = red[0] + red[1] + red[2] + red[3];
  s2 = red[4] + red[5] + red[6] + red[7];
  float mean = s1 * (1.f / 1024.f);
  float var = s2 * (1.f / 1024.f) - mean * mean;
  float rstd = rsqrtf(var + 1e-5f);
  float4 g = ((const float4*)gamma)[tid];
  float4 b = ((const float4*)beta)[tid];
  float4 o;
  o.x = (v0 - mean) * rstd * g.x + b.x;
  o.y = (v1 - mean) * rstd * g.y + b.y;
  o.z = (v2 - mean) * rstd * g.z + b.z;
  o.w = (v3 - mean) * rstd * g.w + b.w;
  ((float4*)(out + row * 1024))[tid] = o;
}

extern "C" void kernel_launch(void* const* d_in, const int* in_sizes, int n_in,
                              void* d_out, int out_size, void* d_ws,
                              size_t ws_size, hipStream_t stream) {
  (void)in_sizes; (void)n_in; (void)out_size; (void)ws_size;
  const float* x  = (const float*)d_in[0];
  const float* WQ = (const float*)d_in[1];
  const float* WK = (const float*)d_in[2];
  const float* WV = (const float*)d_in[3];
  const float* WO = (const float*)d_in[4];
  const float* gamma = (const float*)d_in[5];
  const float* beta  = (const float*)d_in[6];
  float* out = (float*)d_out;

  bf16* ws = (bf16*)d_ws;
  const size_t MD = (size_t)M_ * D_;
  const size_t WW = (size_t)D_ * D_;
  bf16* xb   = ws;
  bf16* wqt  = xb + MD;
  bf16* wkt  = wqt + WW;
  bf16* wvt  = wkt + WW;
  bf16* wot  = wvt + WW;
  bf16* Qb   = wot + WW;
  bf16* Kb   = Qb + MD;
  bf16* Vtb  = Kb + MD;
  bf16* ctxb = Vtb + MD;
  // proj result (bf16) reuses Qb -- dead after attn_kernel.
  bf16* projb = Qb;

  constexpr int GEMM_LDS = 3 * 24 * 1024;  // 73728 B -> 2 blocks/CU
  static bool s_attr = false;
  if (!s_attr) {
    s_attr = true;
    (void)hipFuncSetAttribute(reinterpret_cast<const void*>(gemmA_kernel),
                              hipFuncAttributeMaxDynamicSharedMemorySize,
                              GEMM_LDS);
    (void)hipFuncSetAttribute(reinterpret_cast<const void*>(gemmB_kernel),
                              hipFuncAttributeMaxDynamicSharedMemorySize,
                              GEMM_LDS);
  }

  cvt_all_kernel<<<dim3(8192), dim3(256), 0, stream>>>(
      x, WQ, WK, WV, WO, xb, wqt, wkt, wvt, wot);
  gemmA_kernel<<<dim3(768), dim3(512), GEMM_LDS, stream>>>(
      xb, wqt, wkt, wvt, Qb, Kb, Vtb);
  attn_kernel<<<dim3(512), dim3(512), 0, stream>>>(Qb, Kb, Vtb, ctxb);
  gemmB_kernel<<<dim3(256), dim3(512), GEMM_LDS, stream>>>(
      ctxb, wot, projb);
  ln_kernel<<<dim3(8192), dim3(256), 0, stream>>>(out, projb, xb, gamma, beta);
}